// Round 1
// baseline (2667.178 us; speedup 1.0000x reference)
//
#include <hip/hip_runtime.h>
#include <cmath>

#define BB   2
#define LL   2048
#define DIMD 1024
#define NS   16
#define KC   4
#define ML   (BB*LL)        // 4096 rows (B*L)
#define XZ_N (2*DIMD)       // 2048
#define XD_N (2*NS + DIMD)  // 1056

// ---------------------------------------------------------------------------
// C[M,N] = A[M,K] @ B^T, where B is (N,K) row-major (weights stored (out,in)).
// 64x64 tile, BK=16, 256 threads, 4x4 micro-tile per thread. f32 VALU GEMM.
// M, K assumed multiples of 64/16 (true here: M=4096, K=1024). N guarded.
// ---------------------------------------------------------------------------
template<int BM, int BN, int BK>
__global__ __launch_bounds__(256) void gemm_bt(const float* __restrict__ A,
                                               const float* __restrict__ Bw,
                                               float* __restrict__ C,
                                               int M, int N, int K)
{
    __shared__ float As[BK][BM + 4];
    __shared__ float Bs[BK][BN + 4];

    const int tid = threadIdx.x;
    const int bm = blockIdx.y * BM;
    const int bn = blockIdx.x * BN;

    const int lr = tid >> 2;         // 0..63 : tile row
    const int lc = (tid & 3) << 2;   // 0,4,8,12 : k offset (float4)

    const int tm = (tid & 15) << 2;  // output rows tm..tm+3
    const int tn = (tid >> 4) << 2;  // output cols tn..tn+3

    float acc[4][4] = {};

    for (int k0 = 0; k0 < K; k0 += BK) {
        float4 av = *(const float4*)(A + (size_t)(bm + lr) * K + k0 + lc);
        float4 bv = make_float4(0.f, 0.f, 0.f, 0.f);
        const int brow = bn + lr;
        if (brow < N)
            bv = *(const float4*)(Bw + (size_t)brow * K + k0 + lc);

        __syncthreads();   // protect previous iteration's LDS reads
        As[lc + 0][lr] = av.x; As[lc + 1][lr] = av.y;
        As[lc + 2][lr] = av.z; As[lc + 3][lr] = av.w;
        Bs[lc + 0][lr] = bv.x; Bs[lc + 1][lr] = bv.y;
        Bs[lc + 2][lr] = bv.z; Bs[lc + 3][lr] = bv.w;
        __syncthreads();

        #pragma unroll
        for (int kk = 0; kk < BK; ++kk) {
            float a0 = As[kk][tm + 0], a1 = As[kk][tm + 1];
            float a2 = As[kk][tm + 2], a3 = As[kk][tm + 3];
            float b0 = Bs[kk][tn + 0], b1 = Bs[kk][tn + 1];
            float b2 = Bs[kk][tn + 2], b3 = Bs[kk][tn + 3];
            acc[0][0] = fmaf(a0, b0, acc[0][0]); acc[0][1] = fmaf(a0, b1, acc[0][1]);
            acc[0][2] = fmaf(a0, b2, acc[0][2]); acc[0][3] = fmaf(a0, b3, acc[0][3]);
            acc[1][0] = fmaf(a1, b0, acc[1][0]); acc[1][1] = fmaf(a1, b1, acc[1][1]);
            acc[1][2] = fmaf(a1, b2, acc[1][2]); acc[1][3] = fmaf(a1, b3, acc[1][3]);
            acc[2][0] = fmaf(a2, b0, acc[2][0]); acc[2][1] = fmaf(a2, b1, acc[2][1]);
            acc[2][2] = fmaf(a2, b2, acc[2][2]); acc[2][3] = fmaf(a2, b3, acc[2][3]);
            acc[3][0] = fmaf(a3, b0, acc[3][0]); acc[3][1] = fmaf(a3, b1, acc[3][1]);
            acc[3][2] = fmaf(a3, b2, acc[3][2]); acc[3][3] = fmaf(a3, b3, acc[3][3]);
        }
    }

    #pragma unroll
    for (int i = 0; i < 4; ++i) {
        const int row = bm + tm + i;
        #pragma unroll
        for (int j = 0; j < 4; ++j) {
            const int col = bn + tn + j;
            if (col < N) C[(size_t)row * N + col] = acc[i][j];
        }
    }
}

// ---------------------------------------------------------------------------
// Depthwise causal conv (K=4) + bias + SiLU.  x_c lives in xz[..., :DIMD].
// One thread per (b,l,d) element.
// ---------------------------------------------------------------------------
__global__ __launch_bounds__(256) void conv_silu(const float* __restrict__ xz,
                                                 const float* __restrict__ w,
                                                 const float* __restrict__ bias,
                                                 float* __restrict__ xc)
{
    const int idx = blockIdx.x * blockDim.x + threadIdx.x;
    if (idx >= ML * DIMD) return;
    const int d  = idx & (DIMD - 1);
    const int bl = idx >> 10;          // b*L + l
    const int l  = bl & (LL - 1);

    float acc = bias[d];
    const float* p = xz + (size_t)bl * XZ_N + d;  // x_c[b][l][d]
    #pragma unroll
    for (int t = 0; t < KC; ++t) {
        const int ls = l - (KC - 1) + t;
        if (ls >= 0)
            acc = fmaf(w[d * KC + t], p[(long)(t - (KC - 1)) * XZ_N], acc);
    }
    xc[idx] = acc / (1.f + expf(-acc));   // silu
}

// ---------------------------------------------------------------------------
// Sequential selective scan.  One thread per (b,d); h[16] in registers.
// dA_n = exp(-dt)^(n+1) -> one expf per element, iterated multiply.
// Fuses: softplus(dt), y = scan + D*xc, gating y * silu(z).
// ---------------------------------------------------------------------------
__global__ __launch_bounds__(128) void scan_kernel(const float* __restrict__ xz,
                                                   const float* __restrict__ xc,
                                                   const float* __restrict__ xdbl,
                                                   const float* __restrict__ Dp,
                                                   float* __restrict__ yout)
{
    const int b  = blockIdx.x >> 3;        // 8 d-chunks per batch
    const int dc = blockIdx.x & 7;
    const int d  = dc * 128 + threadIdx.x;

    const float Dv = Dp[d];
    const float* xdbl_b = xdbl + (size_t)b * LL * XD_N;
    const float* xc_b   = xc   + (size_t)b * LL * DIMD;
    const float* xz_b   = xz   + (size_t)b * LL * XZ_N;
    float*       y_b    = yout + (size_t)b * LL * DIMD;

    float h[NS];
    #pragma unroll
    for (int n = 0; n < NS; ++n) h[n] = 0.f;

    for (int l = 0; l < LL; ++l) {
        const float* row = xdbl_b + (size_t)l * XD_N;
        const float dtr = row[2 * NS + d];
        const float dt  = (dtr > 20.f) ? dtr : log1pf(expf(dtr));
        const float xcv = xc_b[(size_t)l * DIMD + d];
        const float zv  = xz_b[(size_t)l * XZ_N + DIMD + d];

        const float e  = expf(-dt);
        const float dx = dt * xcv;
        float p = 1.f;
        float y = 0.f;
        #pragma unroll
        for (int n = 0; n < NS; ++n) {
            p *= e;                               // e^(n+1) = dA_n
            h[n] = fmaf(h[n], p, dx * row[n]);    // h*dA + dt*B*xc
            y = fmaf(h[n], row[NS + n], y);       // + h*C
        }
        const float yv = fmaf(Dv, xcv, y);
        const float sz = zv / (1.f + expf(-zv));  // silu(z)
        y_b[(size_t)l * DIMD + d] = yv * sz;
    }
}

extern "C" void kernel_launch(void* const* d_in, const int* in_sizes, int n_in,
                              void* d_out, int out_size, void* d_ws, size_t ws_size,
                              hipStream_t stream)
{
    const float* x          = (const float*)d_in[0];
    const float* in_proj_w  = (const float*)d_in[1];
    const float* conv_w     = (const float*)d_in[2];
    const float* conv_b     = (const float*)d_in[3];
    const float* x_proj_w   = (const float*)d_in[4];
    const float* D_param    = (const float*)d_in[5];
    const float* out_proj_w = (const float*)d_in[6];
    float* out = (float*)d_out;

    float* xz   = (float*)d_ws;                    // ML * XZ_N
    float* xc   = xz   + (size_t)ML * XZ_N;        // ML * DIMD
    float* xdbl = xc   + (size_t)ML * DIMD;        // ML * XD_N
    float* yfin = xdbl + (size_t)ML * XD_N;        // ML * DIMD

    // 1) xz = x @ in_proj_w.T        (4096 x 2048 x 1024)
    gemm_bt<64, 64, 16><<<dim3(XZ_N / 64, ML / 64), 256, 0, stream>>>(
        x, in_proj_w, xz, ML, XZ_N, DIMD);

    // 2) depthwise conv + bias + silu -> xc
    conv_silu<<<(ML * DIMD) / 256, 256, 0, stream>>>(xz, conv_w, conv_b, xc);

    // 3) x_dbl = xc @ x_proj_w.T     (4096 x 1056 x 1024)
    gemm_bt<64, 64, 16><<<dim3((XD_N + 63) / 64, ML / 64), 256, 0, stream>>>(
        xc, x_proj_w, xdbl, ML, XD_N, DIMD);

    // 4) selective scan + D*xc + silu(z) gating -> yfin
    scan_kernel<<<BB * 8, 128, 0, stream>>>(xz, xc, xdbl, D_param, yfin);

    // 5) out = yfin @ out_proj_w.T   (4096 x 1024 x 1024)
    gemm_bt<64, 64, 16><<<dim3(DIMD / 64, ML / 64), 256, 0, stream>>>(
        yfin, out_proj_w, out, ML, DIMD, DIMD);
}

// Round 2
// 766.463 us; speedup vs baseline: 3.4799x; 3.4799x over previous
//
#include <hip/hip_runtime.h>
#include <cmath>

#define BB   2
#define LL   2048
#define DIMD 1024
#define NS   16
#define KC   4
#define ML   (BB*LL)        // 4096 rows (B*L)
#define XZ_N (2*DIMD)       // 2048
#define XD_N (2*NS + DIMD)  // 1056
#define LC   32             // scan chunk length
#define NC   (LL/LC)        // 64 chunks per sequence

// ---------------------------------------------------------------------------
// C[M,N] = A[M,K] @ B^T, where B is (N,K) row-major (weights stored (out,in)).
// 64x64 tile, BK=16, 256 threads, 4x4 micro-tile per thread. f32 VALU GEMM.
// ---------------------------------------------------------------------------
template<int BM, int BN, int BK>
__global__ __launch_bounds__(256) void gemm_bt(const float* __restrict__ A,
                                               const float* __restrict__ Bw,
                                               float* __restrict__ C,
                                               int M, int N, int K)
{
    __shared__ float As[BK][BM + 4];
    __shared__ float Bs[BK][BN + 4];

    const int tid = threadIdx.x;
    const int bm = blockIdx.y * BM;
    const int bn = blockIdx.x * BN;

    const int lr = tid >> 2;         // 0..63 : tile row
    const int lc = (tid & 3) << 2;   // 0,4,8,12 : k offset (float4)

    const int tm = (tid & 15) << 2;  // output rows tm..tm+3
    const int tn = (tid >> 4) << 2;  // output cols tn..tn+3

    float acc[4][4] = {};

    for (int k0 = 0; k0 < K; k0 += BK) {
        float4 av = *(const float4*)(A + (size_t)(bm + lr) * K + k0 + lc);
        float4 bv = make_float4(0.f, 0.f, 0.f, 0.f);
        const int brow = bn + lr;
        if (brow < N)
            bv = *(const float4*)(Bw + (size_t)brow * K + k0 + lc);

        __syncthreads();   // protect previous iteration's LDS reads
        As[lc + 0][lr] = av.x; As[lc + 1][lr] = av.y;
        As[lc + 2][lr] = av.z; As[lc + 3][lr] = av.w;
        Bs[lc + 0][lr] = bv.x; Bs[lc + 1][lr] = bv.y;
        Bs[lc + 2][lr] = bv.z; Bs[lc + 3][lr] = bv.w;
        __syncthreads();

        #pragma unroll
        for (int kk = 0; kk < BK; ++kk) {
            float a0 = As[kk][tm + 0], a1 = As[kk][tm + 1];
            float a2 = As[kk][tm + 2], a3 = As[kk][tm + 3];
            float b0 = Bs[kk][tn + 0], b1 = Bs[kk][tn + 1];
            float b2 = Bs[kk][tn + 2], b3 = Bs[kk][tn + 3];
            acc[0][0] = fmaf(a0, b0, acc[0][0]); acc[0][1] = fmaf(a0, b1, acc[0][1]);
            acc[0][2] = fmaf(a0, b2, acc[0][2]); acc[0][3] = fmaf(a0, b3, acc[0][3]);
            acc[1][0] = fmaf(a1, b0, acc[1][0]); acc[1][1] = fmaf(a1, b1, acc[1][1]);
            acc[1][2] = fmaf(a1, b2, acc[1][2]); acc[1][3] = fmaf(a1, b3, acc[1][3]);
            acc[2][0] = fmaf(a2, b0, acc[2][0]); acc[2][1] = fmaf(a2, b1, acc[2][1]);
            acc[2][2] = fmaf(a2, b2, acc[2][2]); acc[2][3] = fmaf(a2, b3, acc[2][3]);
            acc[3][0] = fmaf(a3, b0, acc[3][0]); acc[3][1] = fmaf(a3, b1, acc[3][1]);
            acc[3][2] = fmaf(a3, b2, acc[3][2]); acc[3][3] = fmaf(a3, b3, acc[3][3]);
        }
    }

    #pragma unroll
    for (int i = 0; i < 4; ++i) {
        const int row = bm + tm + i;
        #pragma unroll
        for (int j = 0; j < 4; ++j) {
            const int col = bn + tn + j;
            if (col < N) C[(size_t)row * N + col] = acc[i][j];
        }
    }
}

// ---------------------------------------------------------------------------
// Depthwise causal conv (K=4) + bias + SiLU.
// ---------------------------------------------------------------------------
__global__ __launch_bounds__(256) void conv_silu(const float* __restrict__ xz,
                                                 const float* __restrict__ w,
                                                 const float* __restrict__ bias,
                                                 float* __restrict__ xc)
{
    const int idx = blockIdx.x * blockDim.x + threadIdx.x;
    if (idx >= ML * DIMD) return;
    const int d  = idx & (DIMD - 1);
    const int bl = idx >> 10;          // b*L + l
    const int l  = bl & (LL - 1);

    float acc = bias[d];
    const float* p = xz + (size_t)bl * XZ_N + d;  // x_c[b][l][d]
    #pragma unroll
    for (int t = 0; t < KC; ++t) {
        const int ls = l - (KC - 1) + t;
        if (ls >= 0)
            acc = fmaf(w[d * KC + t], p[(long)(t - (KC - 1)) * XZ_N], acc);
    }
    xc[idx] = acc / (1.f + expf(-acc));   // silu
}

__device__ __forceinline__ float softplus_f(float x) {
    return (x > 20.f) ? x : log1pf(expf(x));
}

// ---------------------------------------------------------------------------
// Chunked scan pass 1: one thread per (b, chunk, d). Local scan from h=0;
// emit chunk-final h[16] and S = sum(dt) (decay product per n = exp(-S)^(n+1)).
// ---------------------------------------------------------------------------
__global__ __launch_bounds__(256) void scan_part1(const float* __restrict__ xdbl,
                                                  const float* __restrict__ xc,
                                                  float* __restrict__ hfin,
                                                  float* __restrict__ Ssum)
{
    const int idx = blockIdx.x * blockDim.x + threadIdx.x;  // B*NC*DIMD
    const int d  = idx & (DIMD - 1);
    const int bc = idx >> 10;
    const int c  = bc & (NC - 1);
    const int b  = bc >> 6;
    const int l0 = c * LC;

    const float* xdbl_p = xdbl + ((size_t)b * LL + l0) * XD_N;
    const float* xc_p   = xc   + ((size_t)b * LL + l0) * DIMD + d;

    float h[NS];
    #pragma unroll
    for (int n = 0; n < NS; ++n) h[n] = 0.f;
    float S = 0.f;

    for (int i = 0; i < LC; ++i) {
        const float* row = xdbl_p + (size_t)i * XD_N;
        const float dt = softplus_f(row[2 * NS + d]);
        S += dt;
        const float e  = expf(-dt);
        const float dx = dt * xc_p[(size_t)i * DIMD];
        float p = 1.f;
        #pragma unroll
        for (int n = 0; n < NS; ++n) {
            p *= e;
            h[n] = fmaf(h[n], p, dx * row[n]);
        }
    }

    float* hf = hfin + (size_t)idx * NS;
    #pragma unroll
    for (int n = 0; n < NS; ++n) hf[n] = h[n];
    Ssum[idx] = S;
}

// ---------------------------------------------------------------------------
// Chunked scan pass 2 (combine): one thread per (b,d,n). Walk the NC chunks;
// hfin is rewritten IN PLACE to the carry-in state for each chunk.
// ---------------------------------------------------------------------------
__global__ __launch_bounds__(256) void scan_combine(float* __restrict__ hfin,
                                                    const float* __restrict__ Ssum)
{
    const int idx = blockIdx.x * blockDim.x + threadIdx.x;  // B*DIMD*NS
    const int n = idx & (NS - 1);
    const int d = (idx >> 4) & (DIMD - 1);
    const int b = idx >> 14;
    const float np1 = (float)(n + 1);

    float h = 0.f;
    for (int c = 0; c < NC; ++c) {
        const size_t base = ((size_t)(b * NC + c) * DIMD + d);
        const float S   = Ssum[base];
        const size_t o  = base * NS + n;
        const float tmp = hfin[o];
        hfin[o] = h;                       // carry-in for chunk c
        h = fmaf(h, expf(-S * np1), tmp);  // carry across chunk c
    }
}

// ---------------------------------------------------------------------------
// Chunked scan pass 3: re-run local scan seeded with carry-in; compute
// y = sum(h*C) + D*xc, gate with silu(z), store.
// ---------------------------------------------------------------------------
__global__ __launch_bounds__(256) void scan_part2(const float* __restrict__ xdbl,
                                                  const float* __restrict__ xc,
                                                  const float* __restrict__ xz,
                                                  const float* __restrict__ hfin,
                                                  const float* __restrict__ Dp,
                                                  float* __restrict__ yout)
{
    const int idx = blockIdx.x * blockDim.x + threadIdx.x;  // B*NC*DIMD
    const int d  = idx & (DIMD - 1);
    const int bc = idx >> 10;
    const int c  = bc & (NC - 1);
    const int b  = bc >> 6;
    const int l0 = c * LC;

    const float* xdbl_p = xdbl + ((size_t)b * LL + l0) * XD_N;
    const float* xc_p   = xc   + ((size_t)b * LL + l0) * DIMD + d;
    const float* xz_p   = xz   + ((size_t)b * LL + l0) * XZ_N + DIMD + d;
    float*       y_p    = yout + ((size_t)b * LL + l0) * DIMD + d;

    const float Dv = Dp[d];
    const float* hf = hfin + (size_t)idx * NS;
    float h[NS];
    #pragma unroll
    for (int n = 0; n < NS; ++n) h[n] = hf[n];

    for (int i = 0; i < LC; ++i) {
        const float* row = xdbl_p + (size_t)i * XD_N;
        const float dt  = softplus_f(row[2 * NS + d]);
        const float xcv = xc_p[(size_t)i * DIMD];
        const float zv  = xz_p[(size_t)i * XZ_N];

        const float e  = expf(-dt);
        const float dx = dt * xcv;
        float p = 1.f;
        float y = 0.f;
        #pragma unroll
        for (int n = 0; n < NS; ++n) {
            p *= e;
            h[n] = fmaf(h[n], p, dx * row[n]);
            y = fmaf(h[n], row[NS + n], y);
        }
        const float yv = fmaf(Dv, xcv, y);
        const float sz = zv / (1.f + expf(-zv));  // silu(z)
        y_p[(size_t)i * DIMD] = yv * sz;
    }
}

extern "C" void kernel_launch(void* const* d_in, const int* in_sizes, int n_in,
                              void* d_out, int out_size, void* d_ws, size_t ws_size,
                              hipStream_t stream)
{
    const float* x          = (const float*)d_in[0];
    const float* in_proj_w  = (const float*)d_in[1];
    const float* conv_w     = (const float*)d_in[2];
    const float* conv_b     = (const float*)d_in[3];
    const float* x_proj_w   = (const float*)d_in[4];
    const float* D_param    = (const float*)d_in[5];
    const float* out_proj_w = (const float*)d_in[6];
    float* out = (float*)d_out;

    float* xz   = (float*)d_ws;                    // ML * XZ_N
    float* xc   = xz   + (size_t)ML * XZ_N;        // ML * DIMD
    float* xdbl = xc   + (size_t)ML * DIMD;        // ML * XD_N
    float* yfin = xdbl + (size_t)ML * XD_N;        // ML * DIMD

    // Scan scratch lives in d_out (dead until the final GEMM writes it):
    //   hfin: B*NC*DIMD*NS = 2 MiFloats (8 MB), Ssum: B*NC*DIMD (0.5 MB)
    float* hfin = out;                             // B*NC*DIMD*NS
    float* Ssum = hfin + (size_t)BB * NC * DIMD * NS;

    // 1) xz = x @ in_proj_w.T        (4096 x 2048 x 1024)
    gemm_bt<64, 64, 16><<<dim3(XZ_N / 64, ML / 64), 256, 0, stream>>>(
        x, in_proj_w, xz, ML, XZ_N, DIMD);

    // 2) depthwise conv + bias + silu -> xc
    conv_silu<<<(ML * DIMD) / 256, 256, 0, stream>>>(xz, conv_w, conv_b, xc);

    // 3) x_dbl = xc @ x_proj_w.T     (4096 x 1056 x 1024)
    gemm_bt<64, 64, 16><<<dim3((XD_N + 63) / 64, ML / 64), 256, 0, stream>>>(
        xc, x_proj_w, xdbl, ML, XD_N, DIMD);

    // 4) chunked selective scan
    scan_part1<<<(BB * NC * DIMD) / 256, 256, 0, stream>>>(xdbl, xc, hfin, Ssum);
    scan_combine<<<(BB * DIMD * NS) / 256, 256, 0, stream>>>(hfin, Ssum);
    scan_part2<<<(BB * NC * DIMD) / 256, 256, 0, stream>>>(xdbl, xc, xz, hfin,
                                                           D_param, yfin);

    // 5) out = yfin @ out_proj_w.T   (4096 x 1024 x 1024)
    gemm_bt<64, 64, 16><<<dim3(DIMD / 64, ML / 64), 256, 0, stream>>>(
        yfin, out_proj_w, out, ML, DIMD, DIMD);
}

// Round 3
// 273.506 us; speedup vs baseline: 9.7518x; 2.8024x over previous
//
#include <hip/hip_runtime.h>
#include <cmath>

#define BB   2
#define LL   2048
#define DIMD 1024
#define NS   16
#define KC   4
#define ML   (BB*LL)        // 4096 rows (B*L)
#define XZ_N (2*DIMD)       // 2048
#define XD_N (2*NS + DIMD)  // 1056
#define LC   32             // scan chunk length
#define NC   (LL/LC)        // 64 chunks per sequence

typedef __attribute__((ext_vector_type(8))) short bf16x8;   // 8 bf16 (4 VGPRs)
typedef __attribute__((ext_vector_type(4))) float f32x4;    // MFMA acc

__device__ __forceinline__ unsigned short f2bf(float f) {
    union { float f; unsigned u; } v; v.f = f;
    unsigned r = v.u + 0x7FFF + ((v.u >> 16) & 1);   // round-to-nearest-even
    return (unsigned short)(r >> 16);
}

// ---------------------------------------------------------------------------
// f32 -> bf16 elementwise (n multiple of 4)
// ---------------------------------------------------------------------------
__global__ __launch_bounds__(256) void cvt_bf16(const float* __restrict__ src,
                                                unsigned short* __restrict__ dst,
                                                int n4)
{
    int i = blockIdx.x * blockDim.x + threadIdx.x;
    if (i >= n4) return;
    float4 f = ((const float4*)src)[i];
    ushort4 o;
    o.x = f2bf(f.x); o.y = f2bf(f.y); o.z = f2bf(f.z); o.w = f2bf(f.w);
    ((ushort4*)dst)[i] = o;
}

// ---------------------------------------------------------------------------
// bf16 MFMA GEMM, C[M,N] = A[M,K] @ W[N,K]^T (both row-major, K contiguous).
// 128x128 tile, BK=64, 256 threads = 4 waves, each wave 64x64 via 4x4
// mfma_f32_16x16x32_bf16 frags. global_load_lds width=16 staging with XOR-8
// chunk swizzle (phys_chunk = logical ^ (row&7)) to kill bank conflicts
// (2-way residual aliasing is free per m136). M%128==0, K%64==0; N guarded.
// ---------------------------------------------------------------------------
__global__ __launch_bounds__(256) void gemm_mfma_bt(
    const unsigned short* __restrict__ A,
    const unsigned short* __restrict__ Bw,
    float* __restrict__ C,
    int M, int N, int K)
{
    __shared__ short As[128 * 64];   // 16 KB, row stride 64 bf16 = 128 B
    __shared__ short Bs[128 * 64];

    const int tid  = threadIdx.x;
    const int lane = tid & 63;
    const int wave = tid >> 6;
    const int bm = blockIdx.y * 128;
    const int bn = blockIdx.x * 128;
    const int wm = (wave >> 1) * 64;
    const int wn = (wave & 1) * 64;
    const int l15  = lane & 15;
    const int quad = lane >> 4;

    f32x4 acc[4][4];
    #pragma unroll
    for (int i = 0; i < 4; ++i)
        #pragma unroll
        for (int j = 0; j < 4; ++j)
            acc[i][j] = (f32x4){0.f, 0.f, 0.f, 0.f};

    for (int k0 = 0; k0 < K; k0 += 64) {
        __syncthreads();   // previous iteration's ds_reads done
        #pragma unroll
        for (int q = 0; q < 4; ++q) {
            const int ci = q * 256 + tid;          // linear 16B chunk id
            const int r  = ci >> 3;                // tile row 0..127
            const int cc = (ci & 7) ^ (r & 7);     // swizzled source chunk
            // LDS dst must be wave-uniform: chunk base for this wave's 1KB
            short* ldsA = As + (size_t)(q * 256 + (tid & ~63)) * 8;
            short* ldsB = Bs + (size_t)(q * 256 + (tid & ~63)) * 8;
            const unsigned short* ga = A + (size_t)(bm + r) * K + k0 + cc * 8;
            int rb = bn + r; if (rb > N - 1) rb = N - 1;   // clamp OOB rows
            const unsigned short* gb = Bw + (size_t)rb * K + k0 + cc * 8;
            __builtin_amdgcn_global_load_lds(
                (const __attribute__((address_space(1))) void*)ga,
                (__attribute__((address_space(3))) void*)ldsA, 16, 0, 0);
            __builtin_amdgcn_global_load_lds(
                (const __attribute__((address_space(1))) void*)gb,
                (__attribute__((address_space(3))) void*)ldsB, 16, 0, 0);
        }
        __syncthreads();   // staging visible

        #pragma unroll
        for (int kh = 0; kh < 2; ++kh) {
            bf16x8 af[4], bfr[4];
            #pragma unroll
            for (int i = 0; i < 4; ++i) {
                const int row = wm + i * 16 + l15;
                const int pc  = (kh * 4 + quad) ^ (row & 7);
                af[i] = *(const bf16x8*)(As + row * 64 + pc * 8);
            }
            #pragma unroll
            for (int j = 0; j < 4; ++j) {
                const int row = wn + j * 16 + l15;
                const int pc  = (kh * 4 + quad) ^ (row & 7);
                bfr[j] = *(const bf16x8*)(Bs + row * 64 + pc * 8);
            }
            #pragma unroll
            for (int i = 0; i < 4; ++i)
                #pragma unroll
                for (int j = 0; j < 4; ++j)
                    acc[i][j] = __builtin_amdgcn_mfma_f32_16x16x32_bf16(
                        af[i], bfr[j], acc[i][j], 0, 0, 0);
        }
    }

    // Epilogue: C/D layout col=lane&15, row=quad*4+reg (m89-verified)
    #pragma unroll
    for (int i = 0; i < 4; ++i) {
        const int rbase = bm + wm + i * 16 + quad * 4;
        #pragma unroll
        for (int j = 0; j < 4; ++j) {
            const int col = bn + wn + j * 16 + l15;
            if (col < N) {
                #pragma unroll
                for (int r = 0; r < 4; ++r)
                    C[(size_t)(rbase + r) * N + col] = acc[i][j][r];
            }
        }
    }
}

// ---------------------------------------------------------------------------
// Depthwise causal conv (K=4) + bias + SiLU; writes f32 (for scan) and bf16
// (for the x_proj GEMM).
// ---------------------------------------------------------------------------
__global__ __launch_bounds__(256) void conv_silu(const float* __restrict__ xz,
                                                 const float* __restrict__ w,
                                                 const float* __restrict__ bias,
                                                 float* __restrict__ xc,
                                                 unsigned short* __restrict__ xcb)
{
    const int idx = blockIdx.x * blockDim.x + threadIdx.x;
    if (idx >= ML * DIMD) return;
    const int d  = idx & (DIMD - 1);
    const int bl = idx >> 10;          // b*L + l
    const int l  = bl & (LL - 1);

    float acc = bias[d];
    const float* p = xz + (size_t)bl * XZ_N + d;
    #pragma unroll
    for (int t = 0; t < KC; ++t) {
        const int ls = l - (KC - 1) + t;
        if (ls >= 0)
            acc = fmaf(w[d * KC + t], p[(long)(t - (KC - 1)) * XZ_N], acc);
    }
    const float v = acc / (1.f + expf(-acc));   // silu
    xc[idx] = v;
    xcb[idx] = f2bf(v);
}

__device__ __forceinline__ float softplus_f(float x) {
    return (x > 20.f) ? x : log1pf(expf(x));
}

// ---------------------------------------------------------------------------
// Chunked scan pass 1: thread per (b,chunk,d); local scan from h=0;
// emit chunk-final h[16] and S = sum(dt).
// ---------------------------------------------------------------------------
__global__ __launch_bounds__(256) void scan_part1(const float* __restrict__ xdbl,
                                                  const float* __restrict__ xc,
                                                  float* __restrict__ hfin,
                                                  float* __restrict__ Ssum)
{
    const int idx = blockIdx.x * blockDim.x + threadIdx.x;  // B*NC*DIMD
    const int d  = idx & (DIMD - 1);
    const int bc = idx >> 10;
    const int c  = bc & (NC - 1);
    const int b  = bc >> 6;
    const int l0 = c * LC;

    const float* xdbl_p = xdbl + ((size_t)b * LL + l0) * XD_N;
    const float* xc_p   = xc   + ((size_t)b * LL + l0) * DIMD + d;

    float h[NS];
    #pragma unroll
    for (int n = 0; n < NS; ++n) h[n] = 0.f;
    float S = 0.f;

    for (int i = 0; i < LC; ++i) {
        const float* row = xdbl_p + (size_t)i * XD_N;
        const float dt = softplus_f(row[2 * NS + d]);
        S += dt;
        const float e  = expf(-dt);
        const float dx = dt * xc_p[(size_t)i * DIMD];
        float p = 1.f;
        #pragma unroll
        for (int n = 0; n < NS; ++n) {
            p *= e;
            h[n] = fmaf(h[n], p, dx * row[n]);
        }
    }

    float* hf = hfin + (size_t)idx * NS;
    #pragma unroll
    for (int n = 0; n < NS; ++n) hf[n] = h[n];
    Ssum[idx] = S;
}

// ---------------------------------------------------------------------------
// Chunked scan pass 2 (combine): thread per (b,d,n); hfin rewritten in place
// to carry-in states.
// ---------------------------------------------------------------------------
__global__ __launch_bounds__(256) void scan_combine(float* __restrict__ hfin,
                                                    const float* __restrict__ Ssum)
{
    const int idx = blockIdx.x * blockDim.x + threadIdx.x;  // B*DIMD*NS
    const int n = idx & (NS - 1);
    const int d = (idx >> 4) & (DIMD - 1);
    const int b = idx >> 14;
    const float np1 = (float)(n + 1);

    float h = 0.f;
    for (int c = 0; c < NC; ++c) {
        const size_t base = ((size_t)(b * NC + c) * DIMD + d);
        const float S   = Ssum[base];
        const size_t o  = base * NS + n;
        const float tmp = hfin[o];
        hfin[o] = h;
        h = fmaf(h, expf(-S * np1), tmp);
    }
}

// ---------------------------------------------------------------------------
// Chunked scan pass 3: re-run local scan seeded with carry-in; y = sum(h*C)
// + D*xc, gate silu(z), store bf16 (feeds the out_proj MFMA GEMM).
// ---------------------------------------------------------------------------
__global__ __launch_bounds__(256) void scan_part2(const float* __restrict__ xdbl,
                                                  const float* __restrict__ xc,
                                                  const float* __restrict__ xz,
                                                  const float* __restrict__ hfin,
                                                  const float* __restrict__ Dp,
                                                  unsigned short* __restrict__ yout)
{
    const int idx = blockIdx.x * blockDim.x + threadIdx.x;  // B*NC*DIMD
    const int d  = idx & (DIMD - 1);
    const int bc = idx >> 10;
    const int c  = bc & (NC - 1);
    const int b  = bc >> 6;
    const int l0 = c * LC;

    const float* xdbl_p = xdbl + ((size_t)b * LL + l0) * XD_N;
    const float* xc_p   = xc   + ((size_t)b * LL + l0) * DIMD + d;
    const float* xz_p   = xz   + ((size_t)b * LL + l0) * XZ_N + DIMD + d;
    unsigned short* y_p = yout + ((size_t)b * LL + l0) * DIMD + d;

    const float Dv = Dp[d];
    const float* hf = hfin + (size_t)idx * NS;
    float h[NS];
    #pragma unroll
    for (int n = 0; n < NS; ++n) h[n] = hf[n];

    for (int i = 0; i < LC; ++i) {
        const float* row = xdbl_p + (size_t)i * XD_N;
        const float dt  = softplus_f(row[2 * NS + d]);
        const float xcv = xc_p[(size_t)i * DIMD];
        const float zv  = xz_p[(size_t)i * XZ_N];

        const float e  = expf(-dt);
        const float dx = dt * xcv;
        float p = 1.f;
        float y = 0.f;
        #pragma unroll
        for (int n = 0; n < NS; ++n) {
            p *= e;
            h[n] = fmaf(h[n], p, dx * row[n]);
            y = fmaf(h[n], row[NS + n], y);
        }
        const float yv = fmaf(Dv, xcv, y);
        const float sz = zv / (1.f + expf(-zv));  // silu(z)
        y_p[(size_t)i * DIMD] = f2bf(yv * sz);
    }
}

extern "C" void kernel_launch(void* const* d_in, const int* in_sizes, int n_in,
                              void* d_out, int out_size, void* d_ws, size_t ws_size,
                              hipStream_t stream)
{
    const float* x          = (const float*)d_in[0];
    const float* in_proj_w  = (const float*)d_in[1];
    const float* conv_w     = (const float*)d_in[2];
    const float* conv_b     = (const float*)d_in[3];
    const float* x_proj_w   = (const float*)d_in[4];
    const float* D_param    = (const float*)d_in[5];
    const float* out_proj_w = (const float*)d_in[6];
    float* out = (float*)d_out;

    // workspace layout (~93 MB)
    float* xz   = (float*)d_ws;                               // ML*XZ_N f32
    float* xc   = xz   + (size_t)ML * XZ_N;                   // ML*DIMD f32
    float* xdbl = xc   + (size_t)ML * DIMD;                   // ML*XD_N f32
    unsigned short* xb  = (unsigned short*)(xdbl + (size_t)ML * XD_N); // ML*DIMD bf16
    unsigned short* xcb = xb  + (size_t)ML * DIMD;            // ML*DIMD bf16
    unsigned short* wb1 = xcb + (size_t)ML * DIMD;            // XZ_N*DIMD bf16
    unsigned short* wb2 = wb1 + (size_t)XZ_N * DIMD;          // XD_N*DIMD bf16
    unsigned short* wb3 = wb2 + (size_t)XD_N * DIMD;          // DIMD*DIMD bf16
    unsigned short* yb  = xb;   // xb dead after GEMM1; reuse for scan output

    // scan scratch in d_out (dead until final GEMM): hfin 8.4MB + Ssum 0.5MB
    float* hfin = out;
    float* Ssum = hfin + (size_t)BB * NC * DIMD * NS;

    // 0) bf16 conversions
    cvt_bf16<<<(ML * DIMD / 4 + 255) / 256, 256, 0, stream>>>(x, xb, ML * DIMD / 4);
    cvt_bf16<<<(XZ_N * DIMD / 4 + 255) / 256, 256, 0, stream>>>(in_proj_w, wb1, XZ_N * DIMD / 4);
    cvt_bf16<<<(XD_N * DIMD / 4 + 255) / 256, 256, 0, stream>>>(x_proj_w, wb2, XD_N * DIMD / 4);
    cvt_bf16<<<(DIMD * DIMD / 4 + 255) / 256, 256, 0, stream>>>(out_proj_w, wb3, DIMD * DIMD / 4);

    // 1) xz = x @ in_proj_w.T        (4096 x 2048 x 1024)
    gemm_mfma_bt<<<dim3(XZ_N / 128, ML / 128), 256, 0, stream>>>(
        xb, wb1, xz, ML, XZ_N, DIMD);

    // 2) depthwise conv + bias + silu -> xc (f32) + xcb (bf16)
    conv_silu<<<(ML * DIMD) / 256, 256, 0, stream>>>(xz, conv_w, conv_b, xc, xcb);

    // 3) x_dbl = xc @ x_proj_w.T     (4096 x 1056 x 1024)
    gemm_mfma_bt<<<dim3((XD_N + 127) / 128, ML / 128), 256, 0, stream>>>(
        xcb, wb2, xdbl, ML, XD_N, DIMD);

    // 4) chunked selective scan
    scan_part1<<<(BB * NC * DIMD) / 256, 256, 0, stream>>>(xdbl, xc, hfin, Ssum);
    scan_combine<<<(BB * DIMD * NS) / 256, 256, 0, stream>>>(hfin, Ssum);
    scan_part2<<<(BB * NC * DIMD) / 256, 256, 0, stream>>>(xdbl, xc, xz, hfin,
                                                           D_param, yb);

    // 5) out = y @ out_proj_w.T      (4096 x 1024 x 1024)
    gemm_mfma_bt<<<dim3(DIMD / 128, ML / 128), 256, 0, stream>>>(
        yb, wb3, out, ML, DIMD, DIMD);
}

// Round 5
// 256.887 us; speedup vs baseline: 10.3827x; 1.0647x over previous
//
#include <hip/hip_runtime.h>
#include <cmath>

#define BB   2
#define LL   2048
#define DIMD 1024
#define NS   16
#define KC   4
#define ML   (BB*LL)        // 4096 rows (B*L)
#define XZ_N (2*DIMD)       // 2048
#define XD_N (2*NS + DIMD)  // 1056
#define LC   16             // scan chunk length
#define NC   (LL/LC)        // 128 chunks per sequence

typedef __attribute__((ext_vector_type(8))) short bf16x8;   // 8 bf16 (4 VGPRs)
typedef __attribute__((ext_vector_type(4))) float f32x4;    // MFMA acc

__device__ __forceinline__ unsigned short f2bf(float f) {
    union { float f; unsigned u; } v; v.f = f;
    unsigned r = v.u + 0x7FFF + ((v.u >> 16) & 1);   // round-to-nearest-even
    return (unsigned short)(r >> 16);
}

// ---------------------------------------------------------------------------
// Fused f32 -> bf16 conversion for x + the 3 weight matrices (one launch).
// ---------------------------------------------------------------------------
__global__ __launch_bounds__(256) void cvt_all(
    const float* __restrict__ s0, unsigned short* __restrict__ d0, int n0,
    const float* __restrict__ s1, unsigned short* __restrict__ d1, int n1,
    const float* __restrict__ s2, unsigned short* __restrict__ d2, int n2,
    const float* __restrict__ s3, unsigned short* __restrict__ d3, int n3)
{
    int i = blockIdx.x * blockDim.x + threadIdx.x;
    const float* src; unsigned short* dst;
    if (i < n0)                { src = s0; dst = d0; }
    else if ((i -= n0) < n1)   { src = s1; dst = d1; }
    else if ((i -= n1) < n2)   { src = s2; dst = d2; }
    else if ((i -= n2) < n3)   { src = s3; dst = d3; }
    else return;
    float4 f = ((const float4*)src)[i];
    ushort4 o;
    o.x = f2bf(f.x); o.y = f2bf(f.y); o.z = f2bf(f.z); o.w = f2bf(f.w);
    ((ushort4*)dst)[i] = o;
}

// ---------------------------------------------------------------------------
// bf16 MFMA GEMM, C[M,N] = A[M,K] @ W[N,K]^T (both row-major, K contiguous).
// 128x128 tile, BK=64, 4 waves x 64x64, mfma_f32_16x16x32_bf16 4x4 frags.
// global_load_lds width=16 staging with XOR-8 chunk swizzle. (unchanged)
// ---------------------------------------------------------------------------
__global__ __launch_bounds__(256) void gemm_mfma_bt(
    const unsigned short* __restrict__ A,
    const unsigned short* __restrict__ Bw,
    float* __restrict__ C,
    int M, int N, int K)
{
    __shared__ short As[128 * 64];
    __shared__ short Bs[128 * 64];

    const int tid  = threadIdx.x;
    const int lane = tid & 63;
    const int wave = tid >> 6;
    const int bm = blockIdx.y * 128;
    const int bn = blockIdx.x * 128;
    const int wm = (wave >> 1) * 64;
    const int wn = (wave & 1) * 64;
    const int l15  = lane & 15;
    const int quad = lane >> 4;

    f32x4 acc[4][4];
    #pragma unroll
    for (int i = 0; i < 4; ++i)
        #pragma unroll
        for (int j = 0; j < 4; ++j)
            acc[i][j] = (f32x4){0.f, 0.f, 0.f, 0.f};

    for (int k0 = 0; k0 < K; k0 += 64) {
        __syncthreads();
        #pragma unroll
        for (int q = 0; q < 4; ++q) {
            const int ci = q * 256 + tid;
            const int r  = ci >> 3;
            const int cc = (ci & 7) ^ (r & 7);
            short* ldsA = As + (size_t)(q * 256 + (tid & ~63)) * 8;
            short* ldsB = Bs + (size_t)(q * 256 + (tid & ~63)) * 8;
            const unsigned short* ga = A + (size_t)(bm + r) * K + k0 + cc * 8;
            int rb = bn + r; if (rb > N - 1) rb = N - 1;
            const unsigned short* gb = Bw + (size_t)rb * K + k0 + cc * 8;
            __builtin_amdgcn_global_load_lds(
                (const __attribute__((address_space(1))) void*)ga,
                (__attribute__((address_space(3))) void*)ldsA, 16, 0, 0);
            __builtin_amdgcn_global_load_lds(
                (const __attribute__((address_space(1))) void*)gb,
                (__attribute__((address_space(3))) void*)ldsB, 16, 0, 0);
        }
        __syncthreads();

        #pragma unroll
        for (int kh = 0; kh < 2; ++kh) {
            bf16x8 af[4], bfr[4];
            #pragma unroll
            for (int i = 0; i < 4; ++i) {
                const int row = wm + i * 16 + l15;
                const int pc  = (kh * 4 + quad) ^ (row & 7);
                af[i] = *(const bf16x8*)(As + row * 64 + pc * 8);
            }
            #pragma unroll
            for (int j = 0; j < 4; ++j) {
                const int row = wn + j * 16 + l15;
                const int pc  = (kh * 4 + quad) ^ (row & 7);
                bfr[j] = *(const bf16x8*)(Bs + row * 64 + pc * 8);
            }
            #pragma unroll
            for (int i = 0; i < 4; ++i)
                #pragma unroll
                for (int j = 0; j < 4; ++j)
                    acc[i][j] = __builtin_amdgcn_mfma_f32_16x16x32_bf16(
                        af[i], bfr[j], acc[i][j], 0, 0, 0);
        }
    }

    #pragma unroll
    for (int i = 0; i < 4; ++i) {
        const int rbase = bm + wm + i * 16 + quad * 4;
        #pragma unroll
        for (int j = 0; j < 4; ++j) {
            const int col = bn + wn + j * 16 + l15;
            if (col < N) {
                #pragma unroll
                for (int r = 0; r < 4; ++r)
                    C[(size_t)(rbase + r) * N + col] = acc[i][j][r];
            }
        }
    }
}

// ---------------------------------------------------------------------------
// Depthwise causal conv (K=4) + bias + SiLU; writes f32 + bf16.
// ---------------------------------------------------------------------------
__global__ __launch_bounds__(256) void conv_silu(const float* __restrict__ xz,
                                                 const float* __restrict__ w,
                                                 const float* __restrict__ bias,
                                                 float* __restrict__ xc,
                                                 unsigned short* __restrict__ xcb)
{
    const int idx = blockIdx.x * blockDim.x + threadIdx.x;
    if (idx >= ML * DIMD) return;
    const int d  = idx & (DIMD - 1);
    const int bl = idx >> 10;
    const int l  = bl & (LL - 1);

    float acc = bias[d];
    const float* p = xz + (size_t)bl * XZ_N + d;
    #pragma unroll
    for (int t = 0; t < KC; ++t) {
        const int ls = l - (KC - 1) + t;
        if (ls >= 0)
            acc = fmaf(w[d * KC + t], p[(long)(t - (KC - 1)) * XZ_N], acc);
    }
    const float v = acc / (1.f + expf(-acc));
    xc[idx] = v;
    xcb[idx] = f2bf(v);
}

__device__ __forceinline__ float softplus_f(float x) {
    return (x > 20.f) ? x : log1pf(expf(x));
}

// ---------------------------------------------------------------------------
// Scan pass 1: block = 256 d-lanes of one (b,chunk). B rows staged in LDS;
// per-step B copied to a REAL local array (defined behavior; SROA promotes
// to registers under full unroll). Emit h[16] + S=sum(dt).
// ---------------------------------------------------------------------------
__global__ __launch_bounds__(256) void scan_part1(const float* __restrict__ xdbl,
                                                  const float* __restrict__ xc,
                                                  float* __restrict__ hfin,
                                                  float* __restrict__ Ssum)
{
    __shared__ float Bs[LC][NS];   // 1 KB

    const int tid = threadIdx.x;
    const int idx = blockIdx.x * 256 + tid;   // global (b,c,d)
    const int d   = idx & (DIMD - 1);
    const int bc  = idx >> 10;
    const int c   = bc & (NC - 1);
    const int b   = bc >> 7;
    const int l0  = c * LC;

    const float* xdbl_p = xdbl + ((size_t)b * LL + l0) * XD_N;
    const float* xc_p   = xc   + ((size_t)b * LL + l0) * DIMD + d;

    if (tid < LC * NS / 4) {               // 64 threads stage 16x16 B block
        const int l = tid >> 2, q = tid & 3;
        ((float4*)&Bs[l][0])[q] = ((const float4*)(xdbl_p + (size_t)l * XD_N))[q];
    }
    __syncthreads();

    float h[NS];
    #pragma unroll
    for (int n = 0; n < NS; ++n) h[n] = 0.f;
    float S = 0.f;

    for (int i = 0; i < LC; ++i) {
        const float dt = softplus_f(xdbl_p[(size_t)i * XD_N + 2 * NS + d]);
        S += dt;
        const float e  = expf(-dt);
        const float dx = dt * xc_p[(size_t)i * DIMD];

        alignas(16) float Bf[NS];
        #pragma unroll
        for (int q = 0; q < 4; ++q)
            ((float4*)Bf)[q] = ((const float4*)&Bs[i][0])[q];

        float p = 1.f;
        #pragma unroll
        for (int n = 0; n < NS; ++n) {
            p *= e;
            h[n] = fmaf(h[n], p, dx * Bf[n]);
        }
    }

    float4* hf = (float4*)(hfin + (size_t)idx * NS);
    #pragma unroll
    for (int n = 0; n < 4; ++n) hf[n] = ((float4*)h)[n];
    Ssum[idx] = S;
}

// ---------------------------------------------------------------------------
// Scan pass 2 (combine): thread per (b,d,n); hfin rewritten in place to
// carry-in states.
// ---------------------------------------------------------------------------
__global__ __launch_bounds__(256) void scan_combine(float* __restrict__ hfin,
                                                    const float* __restrict__ Ssum)
{
    const int idx = blockIdx.x * blockDim.x + threadIdx.x;  // B*DIMD*NS
    const int n = idx & (NS - 1);
    const int d = (idx >> 4) & (DIMD - 1);
    const int b = idx >> 14;
    const float np1 = (float)(n + 1);

    float h = 0.f;
    for (int c = 0; c < NC; ++c) {
        const size_t base = ((size_t)(b * NC + c) * DIMD + d);
        const float S   = Ssum[base];
        const size_t o  = base * NS + n;
        const float tmp = hfin[o];
        hfin[o] = h;
        h = fmaf(h, expf(-S * np1), tmp);
    }
}

// ---------------------------------------------------------------------------
// Scan pass 3: B+C rows staged in LDS; re-run local scan seeded with
// carry-in; y = sum(h*C) + D*xc, gate silu(z), store bf16.
// ---------------------------------------------------------------------------
__global__ __launch_bounds__(256) void scan_part2(const float* __restrict__ xdbl,
                                                  const float* __restrict__ xc,
                                                  const float* __restrict__ xz,
                                                  const float* __restrict__ hfin,
                                                  const float* __restrict__ Dp,
                                                  unsigned short* __restrict__ yout)
{
    __shared__ float BCs[LC][2 * NS];   // 2 KB: [l][0..15]=B, [l][16..31]=C

    const int tid = threadIdx.x;
    const int idx = blockIdx.x * 256 + tid;
    const int d   = idx & (DIMD - 1);
    const int bc  = idx >> 10;
    const int c   = bc & (NC - 1);
    const int b   = bc >> 7;
    const int l0  = c * LC;

    const float* xdbl_p = xdbl + ((size_t)b * LL + l0) * XD_N;
    const float* xc_p   = xc   + ((size_t)b * LL + l0) * DIMD + d;
    const float* xz_p   = xz   + ((size_t)b * LL + l0) * XZ_N + DIMD + d;
    unsigned short* y_p = yout + ((size_t)b * LL + l0) * DIMD + d;

    if (tid < LC * 2 * NS / 4) {           // 128 threads stage 16x32 B|C block
        const int l = tid >> 3, q = tid & 7;
        ((float4*)&BCs[l][0])[q] = ((const float4*)(xdbl_p + (size_t)l * XD_N))[q];
    }
    __syncthreads();

    const float Dv = Dp[d];
    float h[NS];
    {
        const float4* hf = (const float4*)(hfin + (size_t)idx * NS);
        #pragma unroll
        for (int n = 0; n < 4; ++n) ((float4*)h)[n] = hf[n];
    }

    for (int i = 0; i < LC; ++i) {
        const float dt  = softplus_f(xdbl_p[(size_t)i * XD_N + 2 * NS + d]);
        const float xcv = xc_p[(size_t)i * DIMD];
        const float zv  = xz_p[(size_t)i * XZ_N];

        const float e  = expf(-dt);
        const float dx = dt * xcv;

        alignas(16) float BCf[2 * NS];
        #pragma unroll
        for (int q = 0; q < 8; ++q)
            ((float4*)BCf)[q] = ((const float4*)&BCs[i][0])[q];

        float p = 1.f;
        float y = 0.f;
        #pragma unroll
        for (int n = 0; n < NS; ++n) {
            p *= e;
            h[n] = fmaf(h[n], p, dx * BCf[n]);
            y = fmaf(h[n], BCf[NS + n], y);
        }
        const float yv = fmaf(Dv, xcv, y);
        const float sz = zv / (1.f + expf(-zv));
        y_p[(size_t)i * DIMD] = f2bf(yv * sz);
    }
}

extern "C" void kernel_launch(void* const* d_in, const int* in_sizes, int n_in,
                              void* d_out, int out_size, void* d_ws, size_t ws_size,
                              hipStream_t stream)
{
    const float* x          = (const float*)d_in[0];
    const float* in_proj_w  = (const float*)d_in[1];
    const float* conv_w     = (const float*)d_in[2];
    const float* conv_b     = (const float*)d_in[3];
    const float* x_proj_w   = (const float*)d_in[4];
    const float* D_param    = (const float*)d_in[5];
    const float* out_proj_w = (const float*)d_in[6];
    float* out = (float*)d_out;

    // workspace layout (~88.6 MiB, same as R3)
    float* xz   = (float*)d_ws;                               // ML*XZ_N f32
    float* xc   = xz   + (size_t)ML * XZ_N;                   // ML*DIMD f32
    float* xdbl = xc   + (size_t)ML * DIMD;                   // ML*XD_N f32
    unsigned short* xb  = (unsigned short*)(xdbl + (size_t)ML * XD_N); // ML*DIMD
    unsigned short* xcb = xb  + (size_t)ML * DIMD;            // ML*DIMD bf16
    unsigned short* wb1 = xcb + (size_t)ML * DIMD;            // XZ_N*DIMD bf16
    unsigned short* wb2 = wb1 + (size_t)XZ_N * DIMD;          // XD_N*DIMD bf16
    unsigned short* wb3 = wb2 + (size_t)XD_N * DIMD;          // DIMD*DIMD bf16
    unsigned short* yb  = xb;    // xb dead after GEMM1; reuse for scan output

    // hfin: B*NC*DIMD*NS floats = 16.8 MB = exact fit in d_out (dead till GEMM3)
    float* hfin = out;
    // Ssum: 1 MB, aliases wb1 (dead after GEMM1; scan runs after GEMM2)
    float* Ssum = (float*)wb1;

    const int n0 = ML * DIMD / 4, n1 = XZ_N * DIMD / 4,
              n2 = XD_N * DIMD / 4, n3 = DIMD * DIMD / 4;
    const int ncvt = n0 + n1 + n2 + n3;

    // 0) all f32->bf16 conversions in one launch
    cvt_all<<<(ncvt + 255) / 256, 256, 0, stream>>>(
        x, xb, n0, in_proj_w, wb1, n1, x_proj_w, wb2, n2, out_proj_w, wb3, n3);

    // 1) xz = x @ in_proj_w.T        (4096 x 2048 x 1024)
    gemm_mfma_bt<<<dim3(XZ_N / 128, ML / 128), 256, 0, stream>>>(
        xb, wb1, xz, ML, XZ_N, DIMD);

    // 2) depthwise conv + bias + silu -> xc (f32) + xcb (bf16)
    conv_silu<<<(ML * DIMD) / 256, 256, 0, stream>>>(xz, conv_w, conv_b, xc, xcb);

    // 3) x_dbl = xc @ x_proj_w.T     (4096 x 1056 x 1024)
    gemm_mfma_bt<<<dim3((XD_N + 127) / 128, ML / 128), 256, 0, stream>>>(
        xcb, wb2, xdbl, ML, XD_N, DIMD);

    // 4) chunked selective scan (LC=16 -> 1024 blocks for part1/part2)
    scan_part1<<<(BB * NC * DIMD) / 256, 256, 0, stream>>>(xdbl, xc, hfin, Ssum);
    scan_combine<<<(BB * DIMD * NS) / 256, 256, 0, stream>>>(hfin, Ssum);
    scan_part2<<<(BB * NC * DIMD) / 256, 256, 0, stream>>>(xdbl, xc, xz, hfin,
                                                           D_param, yb);

    // 5) out = y @ out_proj_w.T      (4096 x 1024 x 1024)
    gemm_mfma_bt<<<dim3(DIMD / 128, ML / 128), 256, 0, stream>>>(
        yb, wb3, out, ML, DIMD, DIMD);
}